// Round 4
// baseline (319.960 us; speedup 1.0000x reference)
//
#include <hip/hip_runtime.h>
#include <stdint.h>

// Problem constants
#define B_   8
#define C_   256
#define N_   2304          // 48*48 spatial
#define HID  128
#define O3   384           // 3*HID
#define NH   4
#define SCALE 0.0625f      // 256^-0.5
#define QPRE 0.09016844f   // SCALE * log2(e): q pre-scale so p = exp2(q.k)

typedef unsigned short u16;
typedef short  bf8  __attribute__((ext_vector_type(8)));   // 8 bf16 (4 VGPRs) MFMA A/B frag
typedef float  f4   __attribute__((ext_vector_type(4)));   // MFMA C/D frag
typedef u16    u16x8 __attribute__((ext_vector_type(8)));

#define MFMA(a,b,c) __builtin_amdgcn_mfma_f32_16x16x32_bf16((a),(b),(c),0,0,0)

static __device__ __forceinline__ u16 f2bf(float f){
    union { float f; unsigned int i; } v; v.f = f;
    unsigned int r = v.i + 0x7FFFu + ((v.i >> 16) & 1u);   // round-to-nearest-even
    return (u16)(r >> 16);
}
static __device__ __forceinline__ float fexp2(float x){
#if __has_builtin(__builtin_amdgcn_exp2f)
    return __builtin_amdgcn_exp2f(x);
#else
    return __expf(x * 0.69314718f);
#endif
}
static __device__ __forceinline__ u16 hi16(float f){       // truncating f32->bf16
    union { float f; unsigned int i; } v; v.f = f;
    return (u16)(v.i >> 16);
}
// async global->LDS DMA, 16B per lane; LDS dest is wave-uniform base + lane*16.
static __device__ __forceinline__ void dma16(const void* g, void* l){
    __builtin_amdgcn_global_load_lds(
        (const __attribute__((address_space(1))) void*)g,
        (__attribute__((address_space(3))) void*)l, 16, 0, 0);
}

// ---------------------------------------------------------------------------
// K0: merged weight prep (one launch).
//   blocks [0,192)  : embed weights fp32 -> bf16  (k_wcvt)
//   blocks [192,448): w_eff^T[s][oc][hc] = sum_head out_w_s[head*HID+hc][oc]
__global__ __launch_bounds__(256) void k_prep(const float* __restrict__ ew0,
                                              const float* __restrict__ ew1,
                                              const float* __restrict__ ow0,
                                              const float* __restrict__ ow1,
                                              u16* __restrict__ Wbf,
                                              u16* __restrict__ weff){
    int bid = blockIdx.x;
    if (bid < 192){
        int s = bid >= 96 ? 1 : 0;
        int xb = bid - s*96;
        const float* w = s ? ew1 : ew0;
        u16* o = Wbf + (size_t)s * (O3 * C_);
        int idx = (xb * 256 + threadIdx.x) * 4;
        float4 v = *reinterpret_cast<const float4*>(&w[idx]);
        o[idx+0] = f2bf(v.x); o[idx+1] = f2bf(v.y);
        o[idx+2] = f2bf(v.z); o[idx+3] = f2bf(v.w);
    } else {
        int gid = (bid - 192) * 256 + threadIdx.x;   // 2*128*256 = 65536
        int oc = gid & 255, hc = (gid >> 8) & 127, s = gid >> 15;
        const float* w = s ? ow1 : ow0;
        float acc = 0.f;
        #pragma unroll
        for (int h = 0; h < NH; ++h) acc += w[(h*HID + hc)*C_ + oc];
        weff[(s*C_ + oc)*HID + hc] = f2bf(acc);
    }
}

// ---------------------------------------------------------------------------
// K1a: transpose+convert X[bs][c][n] fp32 -> Xt[bs][n][c] bf16 (Xt in d_out)
__global__ __launch_bounds__(256) void k_transpose(const float* __restrict__ x0,
                                                   const float* __restrict__ x1,
                                                   u16* __restrict__ Xt){
    __shared__ __align__(16) u16 tile[64][72];
    int z = blockIdx.z, b = z >> 1, s = z & 1;
    const float* X = (s ? x1 : x0) + (size_t)b * (C_ * N_);
    u16* out = Xt + (size_t)z * (N_ * C_);
    int n0 = blockIdx.x * 64, c0 = blockIdx.y * 64;
    int t = threadIdx.x;
    int lr = t >> 4, lc = (t & 15) * 4;
    #pragma unroll
    for (int rep = 0; rep < 4; ++rep){
        int c = lr + rep * 16;
        float4 v = *reinterpret_cast<const float4*>(&X[(size_t)(c0 + c) * N_ + n0 + lc]);
        tile[c][lc+0] = f2bf(v.x); tile[c][lc+1] = f2bf(v.y);
        tile[c][lc+2] = f2bf(v.z); tile[c][lc+3] = f2bf(v.w);
    }
    __syncthreads();
    int row = t >> 3, col8 = (t & 7) * 8;
    #pragma unroll
    for (int rep = 0; rep < 2; ++rep){
        int n = row + rep * 32;
        u16x8 v;
        #pragma unroll
        for (int j = 0; j < 8; ++j) v[j] = tile[col8 + j][n];
        *reinterpret_cast<u16x8*>(&out[(size_t)(n0 + n) * C_ + c0 + col8]) = v;
    }
}

// ---------------------------------------------------------------------------
// K1b: embed GEMM.  Q pre-scaled by QPRE.  K/V written in DMA-friendly
// chunk-interleaved layouts:
//   Kc[z][nc][cc][n&63][8] : elem (n,h) at ((n>>6)*16 + (h>>3))*512 + (n&63)*8 + (h&7)
//   Vc[z][nc][pc][hc][8]   : elem (hc,n) at ((n>>6)*8 + ((n>>3)&7))*1024 + hc*8 + (n&7)
__global__ __launch_bounds__(256, 4) void k_embed(const u16* __restrict__ Xt,
        const u16* __restrict__ Wbf,
        const float* __restrict__ b0, const float* __restrict__ b1,
        u16* __restrict__ Qt, u16* __restrict__ Kc, u16* __restrict__ Vc){
    int z = blockIdx.z, s = z & 1;
    const u16* W = Wbf + (size_t)s * (O3 * C_);
    const float* bias = s ? b1 : b0;
    const u16* Xb = Xt + (size_t)z * (N_ * C_);
    int lane = threadIdx.x & 63, wave = threadIdx.x >> 6;
    int l16 = lane & 15, quad = lane >> 4;
    int o0 = blockIdx.y * 64 + wave * 16;
    int n0 = blockIdx.x * 64;
    f4 acc[4] = {f4{0,0,0,0}, f4{0,0,0,0}, f4{0,0,0,0}, f4{0,0,0,0}};
    #pragma unroll
    for (int kk = 0; kk < 8; ++kk){           // K = 256 = 8 * 32
        bf8 a = *reinterpret_cast<const bf8*>(&W[(o0 + l16) * C_ + kk*32 + quad*8]);
        #pragma unroll
        for (int nt = 0; nt < 4; ++nt){
            bf8 bb = *reinterpret_cast<const bf8*>(&Xb[(size_t)(n0 + nt*16 + l16) * C_ + kk*32 + quad*8]);
            acc[nt] = MFMA(a, bb, acc[nt]);
        }
    }
    size_t zq = (size_t)z * (N_ * HID);
    #pragma unroll
    for (int nt = 0; nt < 4; ++nt){
        int n = n0 + nt*16 + l16;
        #pragma unroll
        for (int r = 0; r < 4; ++r){
            int o = o0 + quad*4 + r;
            float e = acc[nt][r] + bias[o];
            if (o < HID){
                Qt[zq + (size_t)n*HID + o] = f2bf(e * QPRE);
            } else if (o < 2*HID){
                int h = o - HID;
                Kc[zq + ((n>>6)*16 + (h>>3))*512 + ((n&63)<<3) + (h&7)] = f2bf(e);
            } else {
                int hc = o - 2*HID;
                Vc[zq + ((n>>6)*8 + ((n>>3)&7))*1024 + (hc<<3) + (n&7)] = f2bf(e);
            }
        }
    }
}

// ---------------------------------------------------------------------------
// K2 (fused): max-free flash attention + output projection + residual.
//   v5: 32-key chunks with K/V DOUBLE-buffer at only 37.4 KB LDS (>=3 blk/CU,
//   no grid tail -- fixes v2's failure).  Prefetch for chunk nc+1 issued right
//   after the top barrier, so the only vmcnt(0) drain that waits on it (mid
//   barrier) comes after a full QK phase: DMA latency hidden every chunk
//   (fixes v1's structural stall).  Phase-specific wave roles dedup LDS reads
//   (block b128/chunk 68 -> 40): QK waves = 2 row-halves x 2 key-halves (each
//   bk read feeds 2 MFMAs); PV waves = hc-quarters over all rows (each wave
//   reads 4 ap + 2 bv, P is shared in LDS anyway).  Rowsum: wave w accumulates
//   rows [w*16,w*16+16) using its already-loaded ap; shared via 64-f32 LDS in
//   the epilogue (no v3-style 34 KB O-fold).
// LDS map (u16 units):
//   [0,8192)      KV buffer 0: K 16 rows x 256 | V 8 rows x 512 (at +4096)
//   [8192,16384)  KV buffer 1
//   [16384,18688) P shared 64 x 36
//   epilogue: fps 64 f32 at byte 0; Hm 64x136 u16 at byte 512 (KV region dead)
__global__ __launch_bounds__(256, 3) void k_attn_out(const u16* __restrict__ Qt,
        const u16* __restrict__ Kc, const u16* __restrict__ Vc,
        const u16* __restrict__ weff,
        const float* __restrict__ ob0, const float* __restrict__ ob1,
        const float* __restrict__ x0, const float* __restrict__ x1,
        float* __restrict__ out){
    __shared__ __align__(16) u16 lds[18688];           // 37376 B
    int bx = blockIdx.x;                      // 576 = 8 XCD * 72
    int xcd = bx & 7, t = bx >> 3;
    int z  = xcd*2 + (t >= 36 ? 1 : 0);       // XCD x serves z in {2x,2x+1}
    int mt = (t >= 36) ? (t - 36) : t;
    int b = z >> 1, s = z & 1;
    const u16* Q = Qt + (size_t)(b*2 + (1 - s)) * (N_ * HID);
    const u16* K = Kc + (size_t)(b*2 + s)       * (N_ * HID);
    const u16* V = Vc + (size_t)(b*2 + s)       * (N_ * HID);
    const u16* Wf   = weff + (size_t)s * (C_ * HID);
    const float* bias = s ? ob1 : ob0;
    const float* X = (s ? x1 : x0) + (size_t)b * (C_ * N_);
    float* O = out + (size_t)s * ((size_t)B_ * C_ * N_) + (size_t)b * (C_ * N_);
    int lane = threadIdx.x & 63, wave = threadIdx.x >> 6;
    int l16 = lane & 15, quad = lane >> 4;
    int rw = wave & 1, kw = wave >> 1;        // QK-phase role: row-half, key-half

    // Q fragments for QK rows [mt*64 + rw*32, +32): 2 row-tiles x 4 k-slices
    int m0q = mt * 64 + rw * 32;
    bf8 aq[2][4];
    #pragma unroll
    for (int rt = 0; rt < 2; ++rt)
        #pragma unroll
        for (int kk = 0; kk < 4; ++kk)
            aq[rt][kk] = *reinterpret_cast<const bf8*>(
                &Q[(size_t)(m0q + rt*16 + l16)*HID + kk*32 + quad*8]);

    bf8 ones;
    #pragma unroll
    for (int j = 0; j < 8; ++j) ones[j] = (short)0x3F80;   // bf16 1.0

    // PV-phase role: this wave owns hc [wave*32, wave*32+32) for ALL 64 rows.
    f4 oacc[4][2];
    #pragma unroll
    for (int rt4 = 0; rt4 < 4; ++rt4)
        #pragma unroll
        for (int c = 0; c < 2; ++c) oacc[rt4][c] = f4{0,0,0,0};
    f4 sumacc = f4{0,0,0,0};                   // rowsum for rows [wave*16,+16)

    u16* P = lds + 16384;                      // shared 64 x 36 P tile

    // ---- staging helper (inlined twice): chunk nc -> buffer bsel ------------
    // K 32-key tile: 16 rows (cc = h>>3) x 256 u16; row cc = keys 0..31 x h&7.
    // V 32-key tile: 4 rows (pc = key>>3) x 1024 u16; row pc = hc*8 + key&7.
#define STAGE(nc_, bsel_) do {                                               \
        int c64 = (nc_) >> 1, half = (nc_) & 1;                              \
        u16* kb_ = lds + (bsel_)*8192;                                       \
        u16* vb_ = kb_ + 4096;                                               \
        const u16* Ksrc = K + (size_t)c64*8192 + half*256;                   \
        _Pragma("unroll")                                                    \
        for (int j = 0; j < 2; ++j){                                         \
            int cc = wave*4 + j*2;                                           \
            dma16(Ksrc + (size_t)(cc + (lane>>5))*512 + (lane&31)*8,         \
                  &kb_[cc*256]);                                             \
        }                                                                    \
        const u16* Vsrc = V + (size_t)c64*8192 + half*4096;                  \
        _Pragma("unroll")                                                    \
        for (int j = 0; j < 2; ++j){                                         \
            int rv = wave*2 + j;                                             \
            dma16(Vsrc + (size_t)rv*512 + lane*8, &vb_[rv*512]);             \
        }                                                                    \
    } while(0)

    STAGE(0, 0);                               // prologue: chunk 0 -> buffer 0

    for (int nc = 0; nc < N_/32; ++nc){
        int cur = nc & 1;
        // top barrier: protects buf[cur^1] (PV of nc-1 done) and P (ap reads of
        // nc-1 done).  No DMA outstanding per-wave here (drained at prev mid).
        __syncthreads();
        if (nc + 1 < N_/32) STAGE(nc + 1, cur ^ 1);   // issue early; drains at mid
        const u16* kb = lds + cur*8192;
        const u16* vb = kb + 4096;
        // QK: rows [m0q, m0q+32) x keys [kw*16, kw*16+16) of chunk nc
        f4 sacc[2] = {f4{0,0,0,0}, f4{0,0,0,0}};
        __builtin_amdgcn_s_setprio(1);
        #pragma unroll
        for (int kk = 0; kk < 4; ++kk){
            bf8 bk = *reinterpret_cast<const bf8*>(
                &kb[(kk*4 + quad)*256 + (kw*16 + l16)*8]);
            sacc[0] = MFMA(aq[0][kk], bk, sacc[0]);   // 1 read -> 2 MFMA
            sacc[1] = MFMA(aq[1][kk], bk, sacc[1]);
        }
        __builtin_amdgcn_s_setprio(0);
        // p = exp2(s) -> shared P tile
        #pragma unroll
        for (int rt = 0; rt < 2; ++rt)
            #pragma unroll
            for (int r = 0; r < 4; ++r)
                P[(rw*32 + rt*16 + quad*4 + r)*36 + kw*16 + l16]
                    = hi16(fexp2(sacc[rt][r]));
        // mid barrier: P visible to all waves; drains prefetch DMA (hidden
        // under the QK phase above).
        __syncthreads();
        // PV: this wave's hc slice for all 64 rows; K-dim = 32 keys.
        bf8 bv[2];
        #pragma unroll
        for (int c = 0; c < 2; ++c)
            bv[c] = *reinterpret_cast<const bf8*>(
                &vb[quad*1024 + ((wave*2 + c)*16 + l16)*8]);
        __builtin_amdgcn_s_setprio(1);
        #pragma unroll
        for (int rt4 = 0; rt4 < 4; ++rt4){
            bf8 ap = *reinterpret_cast<const bf8*>(&P[(rt4*16 + l16)*36 + quad*8]);
            if (rt4 == wave) sumacc = MFMA(ap, ones, sumacc);
            oacc[rt4][0] = MFMA(ap, bv[0], oacc[rt4][0]);
            oacc[rt4][1] = MFMA(ap, bv[1], oacc[rt4][1]);
        }
        __builtin_amdgcn_s_setprio(0);
    }
#undef STAGE

    // ---- epilogue: share rowsums, normalize, out-GEMM -----------------------
    __syncthreads();                           // all P/V LDS reads done
    float* fps = (float*)lds;                  // 64 f32 rowsums
    u16*  Hm   = lds + 256;                    // byte 512: 64 x 136 u16 H tile
    if (l16 == 0){
        #pragma unroll
        for (int r = 0; r < 4; ++r)
            fps[wave*16 + quad*4 + r] = sumacc[r];  // cols identical; lane 0 writes
    }
    __syncthreads();
    float inv[4][4];
    #pragma unroll
    for (int rt4 = 0; rt4 < 4; ++rt4)
        #pragma unroll
        for (int r = 0; r < 4; ++r)
            inv[rt4][r] = 1.0f / fps[rt4*16 + quad*4 + r];
    #pragma unroll
    for (int rt4 = 0; rt4 < 4; ++rt4)
        #pragma unroll
        for (int c = 0; c < 2; ++c)
            #pragma unroll
            for (int r = 0; r < 4; ++r)
                Hm[(rt4*16 + quad*4 + r)*136 + (wave*2 + c)*16 + l16]
                    = f2bf(oacc[rt4][c][r] * inv[rt4][r]);
    __syncthreads();

    // out GEMM: wave w -> oc [w*64, w*64+64); K = HID = 128
    int mb = mt * 64;
    int oc0 = wave * 64;
    f4 acc2[4][4];
    #pragma unroll
    for (int ot = 0; ot < 4; ++ot)
        #pragma unroll
        for (int nt = 0; nt < 4; ++nt) acc2[ot][nt] = f4{0,0,0,0};
    #pragma unroll
    for (int kk = 0; kk < 4; ++kk){
        bf8 bh[4];
        #pragma unroll
        for (int nt = 0; nt < 4; ++nt)
            bh[nt] = *reinterpret_cast<const bf8*>(&Hm[(nt*16 + l16)*136 + kk*32 + quad*8]);
        #pragma unroll
        for (int ot = 0; ot < 4; ++ot){
            bf8 a = *reinterpret_cast<const bf8*>(&Wf[(oc0 + ot*16 + l16)*HID + kk*32 + quad*8]);
            #pragma unroll
            for (int nt = 0; nt < 4; ++nt)
                acc2[ot][nt] = MFMA(a, bh[nt], acc2[ot][nt]);
        }
    }
    #pragma unroll
    for (int ot = 0; ot < 4; ++ot)
        #pragma unroll
        for (int nt = 0; nt < 4; ++nt){
            int m = mb + nt*16 + l16;
            #pragma unroll
            for (int r = 0; r < 4; ++r){
                int oc = oc0 + ot*16 + quad*4 + r;
                O[(size_t)oc*N_ + m] = acc2[ot][nt][r] + bias[oc] + X[(size_t)oc*N_ + m];
            }
        }
}

// ---------------------------------------------------------------------------
extern "C" void kernel_launch(void* const* d_in, const int* in_sizes, int n_in,
                              void* d_out, int out_size, void* d_ws, size_t ws_size,
                              hipStream_t stream){
    const float* x0  = (const float*)d_in[0];
    const float* x1  = (const float*)d_in[1];
    const float* ew0 = (const float*)d_in[2];
    const float* eb0 = (const float*)d_in[3];
    const float* ew1 = (const float*)d_in[4];
    const float* eb1 = (const float*)d_in[5];
    const float* ow0 = (const float*)d_in[6];
    const float* ob0 = (const float*)d_in[7];
    const float* ow1 = (const float*)d_in[8];
    const float* ob1 = (const float*)d_in[9];

    u16* ws = (u16*)d_ws;
    const size_t QT_E = (size_t)16 * N_ * HID;
    u16* Qt   = ws;
    u16* Kc   = Qt + QT_E;
    u16* Vc   = Kc + QT_E;
    u16* Wbf  = Vc + QT_E;
    u16* weff = Wbf + (size_t)2 * O3 * C_;
    u16* Xt   = (u16*)d_out;                  // scratch phase

    k_prep     <<<dim3(448),       dim3(256), 0, stream>>>(ew0, ew1, ow0, ow1, Wbf, weff);
    k_transpose<<<dim3(36, 4, 16), dim3(256), 0, stream>>>(x0, x1, Xt);
    k_embed    <<<dim3(36, 6, 16), dim3(256), 0, stream>>>(Xt, Wbf, eb0, eb1, Qt, Kc, Vc);
    k_attn_out <<<dim3(576),       dim3(256), 0, stream>>>(Qt, Kc, Vc, weff, ob0, ob1,
                                                           x0, x1, (float*)d_out);
}

// Round 5
// 272.018 us; speedup vs baseline: 1.1762x; 1.1762x over previous
//
#include <hip/hip_runtime.h>
#include <stdint.h>

// Problem constants
#define B_   8
#define C_   256
#define N_   2304          // 48*48 spatial
#define HID  128
#define O3   384           // 3*HID
#define NH   4
#define SCALE 0.0625f      // 256^-0.5
#define QPRE 0.09016844f   // SCALE * log2(e): q pre-scale so p = exp2(q.k)

typedef unsigned short u16;
typedef short  bf8  __attribute__((ext_vector_type(8)));   // 8 bf16 (4 VGPRs) MFMA A/B frag
typedef float  f4   __attribute__((ext_vector_type(4)));   // MFMA C/D frag
typedef u16    u16x8 __attribute__((ext_vector_type(8)));

#define MFMA(a,b,c) __builtin_amdgcn_mfma_f32_16x16x32_bf16((a),(b),(c),0,0,0)

static __device__ __forceinline__ u16 f2bf(float f){
    union { float f; unsigned int i; } v; v.f = f;
    unsigned int r = v.i + 0x7FFFu + ((v.i >> 16) & 1u);   // round-to-nearest-even
    return (u16)(r >> 16);
}
static __device__ __forceinline__ float fexp2(float x){
#if __has_builtin(__builtin_amdgcn_exp2f)
    return __builtin_amdgcn_exp2f(x);
#else
    return __expf(x * 0.69314718f);
#endif
}
static __device__ __forceinline__ u16 hi16(float f){       // truncating f32->bf16
    union { float f; unsigned int i; } v; v.f = f;
    return (u16)(v.i >> 16);
}
// async global->LDS DMA, 16B per lane; LDS dest is wave-uniform base + lane*16.
static __device__ __forceinline__ void dma16(const void* g, void* l){
    __builtin_amdgcn_global_load_lds(
        (const __attribute__((address_space(1))) void*)g,
        (__attribute__((address_space(3))) void*)l, 16, 0, 0);
}

// ---------------------------------------------------------------------------
// K0: merged weight prep (one launch).
//   blocks [0,192)  : embed weights fp32 -> bf16
//   blocks [192,448): w_eff^T[s][oc][hc] = sum_head out_w_s[head*HID+hc][oc]
__global__ __launch_bounds__(256) void k_prep(const float* __restrict__ ew0,
                                              const float* __restrict__ ew1,
                                              const float* __restrict__ ow0,
                                              const float* __restrict__ ow1,
                                              u16* __restrict__ Wbf,
                                              u16* __restrict__ weff){
    int bid = blockIdx.x;
    if (bid < 192){
        int s = bid >= 96 ? 1 : 0;
        int xb = bid - s*96;
        const float* w = s ? ew1 : ew0;
        u16* o = Wbf + (size_t)s * (O3 * C_);
        int idx = (xb * 256 + threadIdx.x) * 4;
        float4 v = *reinterpret_cast<const float4*>(&w[idx]);
        o[idx+0] = f2bf(v.x); o[idx+1] = f2bf(v.y);
        o[idx+2] = f2bf(v.z); o[idx+3] = f2bf(v.w);
    } else {
        int gid = (bid - 192) * 256 + threadIdx.x;   // 2*128*256 = 65536
        int oc = gid & 255, hc = (gid >> 8) & 127, s = gid >> 15;
        const float* w = s ? ow1 : ow0;
        float acc = 0.f;
        #pragma unroll
        for (int h = 0; h < NH; ++h) acc += w[(h*HID + hc)*C_ + oc];
        weff[(s*C_ + oc)*HID + hc] = f2bf(acc);
    }
}

// ---------------------------------------------------------------------------
// K1a: transpose+convert X[bs][c][n] fp32 -> Xt[bs][n][c] bf16 (Xt in d_out)
__global__ __launch_bounds__(256) void k_transpose(const float* __restrict__ x0,
                                                   const float* __restrict__ x1,
                                                   u16* __restrict__ Xt){
    __shared__ __align__(16) u16 tile[64][72];
    int z = blockIdx.z, b = z >> 1, s = z & 1;
    const float* X = (s ? x1 : x0) + (size_t)b * (C_ * N_);
    u16* out = Xt + (size_t)z * (N_ * C_);
    int n0 = blockIdx.x * 64, c0 = blockIdx.y * 64;
    int t = threadIdx.x;
    int lr = t >> 4, lc = (t & 15) * 4;
    #pragma unroll
    for (int rep = 0; rep < 4; ++rep){
        int c = lr + rep * 16;
        float4 v = *reinterpret_cast<const float4*>(&X[(size_t)(c0 + c) * N_ + n0 + lc]);
        tile[c][lc+0] = f2bf(v.x); tile[c][lc+1] = f2bf(v.y);
        tile[c][lc+2] = f2bf(v.z); tile[c][lc+3] = f2bf(v.w);
    }
    __syncthreads();
    int row = t >> 3, col8 = (t & 7) * 8;
    #pragma unroll
    for (int rep = 0; rep < 2; ++rep){
        int n = row + rep * 32;
        u16x8 v;
        #pragma unroll
        for (int j = 0; j < 8; ++j) v[j] = tile[col8 + j][n];
        *reinterpret_cast<u16x8*>(&out[(size_t)(n0 + n) * C_ + c0 + col8]) = v;
    }
}

// ---------------------------------------------------------------------------
// K1b: embed GEMM.  Q pre-scaled by QPRE.  K/V written in fragment-coalesced
// chunk-interleaved layouts:
//   Kc[z][nc][cc][n&63][8] : elem (n,h) at ((n>>6)*16 + (h>>3))*512 + (n&63)*8 + (h&7)
//   Vc[z][nc][pc][hc][8]   : elem (hc,n) at ((n>>6)*8 + ((n>>3)&7))*1024 + hc*8 + (n&7)
__global__ __launch_bounds__(256, 4) void k_embed(const u16* __restrict__ Xt,
        const u16* __restrict__ Wbf,
        const float* __restrict__ b0, const float* __restrict__ b1,
        u16* __restrict__ Qt, u16* __restrict__ Kc, u16* __restrict__ Vc){
    int z = blockIdx.z, s = z & 1;
    const u16* W = Wbf + (size_t)s * (O3 * C_);
    const float* bias = s ? b1 : b0;
    const u16* Xb = Xt + (size_t)z * (N_ * C_);
    int lane = threadIdx.x & 63, wave = threadIdx.x >> 6;
    int l16 = lane & 15, quad = lane >> 4;
    int o0 = blockIdx.y * 64 + wave * 16;
    int n0 = blockIdx.x * 64;
    f4 acc[4] = {f4{0,0,0,0}, f4{0,0,0,0}, f4{0,0,0,0}, f4{0,0,0,0}};
    #pragma unroll
    for (int kk = 0; kk < 8; ++kk){           // K = 256 = 8 * 32
        bf8 a = *reinterpret_cast<const bf8*>(&W[(o0 + l16) * C_ + kk*32 + quad*8]);
        #pragma unroll
        for (int nt = 0; nt < 4; ++nt){
            bf8 bb = *reinterpret_cast<const bf8*>(&Xb[(size_t)(n0 + nt*16 + l16) * C_ + kk*32 + quad*8]);
            acc[nt] = MFMA(a, bb, acc[nt]);
        }
    }
    size_t zq = (size_t)z * (N_ * HID);
    #pragma unroll
    for (int nt = 0; nt < 4; ++nt){
        int n = n0 + nt*16 + l16;
        #pragma unroll
        for (int r = 0; r < 4; ++r){
            int o = o0 + quad*4 + r;
            float e = acc[nt][r] + bias[o];
            if (o < HID){
                Qt[zq + (size_t)n*HID + o] = f2bf(e * QPRE);
            } else if (o < 2*HID){
                int h = o - HID;
                Kc[zq + ((n>>6)*16 + (h>>3))*512 + ((n&63)<<3) + (h&7)] = f2bf(e);
            } else {
                int hc = o - 2*HID;
                Vc[zq + ((n>>6)*8 + ((n>>3)&7))*1024 + (hc<<3) + (n&7)] = f2bf(e);
            }
        }
    }
}

// ---------------------------------------------------------------------------
// K2 (fused): max-free flash attention + output projection + residual.
//   v6 = v1 (96.6 us baseline structure, 64-key chunks, per-wave 16 rows x all
//   keys, per-wave P dbuf) with the sync structure fixed:
//    * K double-buffered in LDS (2 x 16 KB).  Prefetch for chunk nc+1 issued
//      right after the top barrier of chunk nc; the ONLY vmcnt(0) drain that
//      waits on it is the top barrier of chunk nc+1 -- a full chunk (~600 cyc)
//      later, so DMA latency is fully hidden (v2's property) at v1's LDS cost.
//    * V loaded global->VGPR direct (16 frags, 64 VGPR transient), issued at
//      chunk top, consumed in PV after QK: ~400 cyc of cover for the L2 hit
//      (V is XCD-L2-resident).  V's LDS round-trip deleted.
//    * ONE __syncthreads per chunk (36 total vs v1's 72).
//   Budget: LDS 51200 B (= v1), VGPR+AGPR ~146 <= 170 -> 3 blocks/CU, all 576
//   blocks resident, no tail.
// LDS map (u16 units): [0,8192) K buf0 | [8192,16384) K buf1
//                      [16384,25600) P tiles (4 waves x dbuf x 16x72)
//   epilogue: H tile 64x136 u16 at u16 offset 16384 (P region, after barrier)
__global__ __launch_bounds__(256, 3) void k_attn_out(const u16* __restrict__ Qt,
        const u16* __restrict__ Kc, const u16* __restrict__ Vc,
        const u16* __restrict__ weff,
        const float* __restrict__ ob0, const float* __restrict__ ob1,
        const float* __restrict__ x0, const float* __restrict__ x1,
        float* __restrict__ out){
    __shared__ __align__(16) u16 lds[25600];           // 51200 B -> 3 blocks/CU
    int bx = blockIdx.x;                      // 576 = 8 XCD * 72
    int xcd = bx & 7, t = bx >> 3;
    int z  = xcd*2 + (t >= 36 ? 1 : 0);       // XCD x serves z in {2x,2x+1}
    int mt = (t >= 36) ? (t - 36) : t;
    int b = z >> 1, s = z & 1;
    const u16* Q = Qt + (size_t)(b*2 + (1 - s)) * (N_ * HID);
    const u16* K = Kc + (size_t)(b*2 + s)       * (N_ * HID);
    const u16* V = Vc + (size_t)(b*2 + s)       * (N_ * HID);
    const u16* Wf   = weff + (size_t)s * (C_ * HID);
    const float* bias = s ? ob1 : ob0;
    const float* X = (s ? x1 : x0) + (size_t)b * (C_ * N_);
    float* O = out + (size_t)s * ((size_t)B_ * C_ * N_) + (size_t)b * (C_ * N_);
    int lane = threadIdx.x & 63, wave = threadIdx.x >> 6;
    int l16 = lane & 15, quad = lane >> 4;
    int m0 = mt * 64 + wave * 16;

    // Q fragments for this wave's 16 rows
    bf8 aq[4];
    #pragma unroll
    for (int kk = 0; kk < 4; ++kk)
        aq[kk] = *reinterpret_cast<const bf8*>(&Q[(size_t)(m0 + l16)*HID + kk*32 + quad*8]);

    bf8 ones;
    #pragma unroll
    for (int j = 0; j < 8; ++j) ones[j] = (short)0x3F80;   // bf16 1.0

    f4 oacc[8];
    #pragma unroll
    for (int ct = 0; ct < 8; ++ct) oacc[ct] = f4{0,0,0,0};
    f4 sumacc = f4{0,0,0,0};

    const char* Kb = (const char*)K;
    // per-lane V fragment base: frag(kk2,ct) of chunk nc at
    //   vq[nc*8192 + kk2*4096 + ct*128]   (16 B contiguous per lane)
    const u16* vq = V + quad*1024 + l16*8;

    // K staging: chunk nc_ -> K buffer bsel_ (16 x 1 KB coalesced bursts)
#define STAGE_K(nc_, bsel_) do {                                             \
        u16* kb_ = lds + (bsel_)*8192;                                       \
        _Pragma("unroll")                                                    \
        for (int j = 0; j < 4; ++j){                                         \
            int ik = wave*4 + j;                                             \
            dma16(Kb + ((size_t)((nc_)*16 + ik)*512 + lane*8)*2,             \
                  &kb_[ik*512]);                                             \
        }                                                                    \
    } while(0)

    STAGE_K(0, 0);                             // prologue: chunk 0 -> buf 0

    for (int nc = 0; nc < N_/64; ++nc){
        int cur = nc & 1;
        // single barrier per chunk: (a) drains the K-DMA for chunk nc (issued
        // one full chunk ago -> latency hidden), (b) guarantees all waves are
        // done reading K buf[cur^1] before its overwrite below.
        __syncthreads();
        if (nc + 1 < N_/64) STAGE_K(nc + 1, cur ^ 1);
        // V direct loads for this chunk; consumed in PV (~QK-phase later)
        bf8 vf[16];
        {
            size_t voff = (size_t)nc * 8192;
            #pragma unroll
            for (int kk2 = 0; kk2 < 2; ++kk2)
                #pragma unroll
                for (int ct = 0; ct < 8; ++ct)
                    vf[kk2*8 + ct] = *reinterpret_cast<const bf8*>(
                        &vq[voff + kk2*4096 + ct*128]);
        }
        const u16* kb = lds + cur*8192;
        // QK: rows [m0, m0+16) x all 64 keys of chunk nc
        f4 sacc[4] = {f4{0,0,0,0}, f4{0,0,0,0}, f4{0,0,0,0}, f4{0,0,0,0}};
        __builtin_amdgcn_s_setprio(1);
        #pragma unroll
        for (int kk = 0; kk < 4; ++kk)
            #pragma unroll
            for (int nt = 0; nt < 4; ++nt){
                bf8 bk = *reinterpret_cast<const bf8*>(
                    &kb[((kk*4 + quad)*64 + nt*16 + l16)*8]);
                sacc[nt] = MFMA(aq[kk], bk, sacc[nt]);
            }
        __builtin_amdgcn_s_setprio(0);
        // p = exp2(s), truncating bf16 store to per-wave P tile (dbuf)
        u16* pw = lds + 16384 + (wave*2 + cur) * (16*72);
        #pragma unroll
        for (int nt = 0; nt < 4; ++nt)
            #pragma unroll
            for (int r = 0; r < 4; ++r)
                pw[(quad*4 + r)*72 + nt*16 + l16] = hi16(fexp2(sacc[nt][r]));
        // PV + rowsum; V from registers
        __builtin_amdgcn_s_setprio(1);
        #pragma unroll
        for (int kk2 = 0; kk2 < 2; ++kk2){
            bf8 ap = *reinterpret_cast<const bf8*>(&pw[l16*72 + kk2*32 + quad*8]);
            sumacc = MFMA(ap, ones, sumacc);
            #pragma unroll
            for (int ct = 0; ct < 8; ++ct)
                oacc[ct] = MFMA(ap, vf[kk2*8 + ct], oacc[ct]);
        }
        __builtin_amdgcn_s_setprio(0);
    }
#undef STAGE_K

    // ---- epilogue: normalize (lane-local) and stash H -----------------------
    __syncthreads();                           // P region dead in all waves
    u16* Hm = lds + 16384;                     // 64 x 136 u16 H tile
    float inv[4];
    #pragma unroll
    for (int r = 0; r < 4; ++r) inv[r] = 1.0f / sumacc[r];
    #pragma unroll
    for (int ct = 0; ct < 8; ++ct)
        #pragma unroll
        for (int r = 0; r < 4; ++r)
            Hm[(wave*16 + quad*4 + r)*136 + ct*16 + l16] = f2bf(oacc[ct][r] * inv[r]);
    __syncthreads();

    // out GEMM: wave w -> oc [w*64, w*64+64); K = HID = 128
    int mb = mt * 64;
    int oc0 = wave * 64;
    f4 acc2[4][4];
    #pragma unroll
    for (int ot = 0; ot < 4; ++ot)
        #pragma unroll
        for (int nt = 0; nt < 4; ++nt) acc2[ot][nt] = f4{0,0,0,0};
    #pragma unroll
    for (int kk = 0; kk < 4; ++kk){
        bf8 bh[4];
        #pragma unroll
        for (int nt = 0; nt < 4; ++nt)
            bh[nt] = *reinterpret_cast<const bf8*>(&Hm[(nt*16 + l16)*136 + kk*32 + quad*8]);
        #pragma unroll
        for (int ot = 0; ot < 4; ++ot){
            bf8 a = *reinterpret_cast<const bf8*>(&Wf[(oc0 + ot*16 + l16)*HID + kk*32 + quad*8]);
            #pragma unroll
            for (int nt = 0; nt < 4; ++nt)
                acc2[ot][nt] = MFMA(a, bh[nt], acc2[ot][nt]);
        }
    }
    #pragma unroll
    for (int ot = 0; ot < 4; ++ot)
        #pragma unroll
        for (int nt = 0; nt < 4; ++nt){
            int m = mb + nt*16 + l16;
            #pragma unroll
            for (int r = 0; r < 4; ++r){
                int oc = oc0 + ot*16 + quad*4 + r;
                O[(size_t)oc*N_ + m] = acc2[ot][nt][r] + bias[oc] + X[(size_t)oc*N_ + m];
            }
        }
}

// ---------------------------------------------------------------------------
extern "C" void kernel_launch(void* const* d_in, const int* in_sizes, int n_in,
                              void* d_out, int out_size, void* d_ws, size_t ws_size,
                              hipStream_t stream){
    const float* x0  = (const float*)d_in[0];
    const float* x1  = (const float*)d_in[1];
    const float* ew0 = (const float*)d_in[2];
    const float* eb0 = (const float*)d_in[3];
    const float* ew1 = (const float*)d_in[4];
    const float* eb1 = (const float*)d_in[5];
    const float* ow0 = (const float*)d_in[6];
    const float* ob0 = (const float*)d_in[7];
    const float* ow1 = (const float*)d_in[8];
    const float* ob1 = (const float*)d_in[9];

    u16* ws = (u16*)d_ws;
    const size_t QT_E = (size_t)16 * N_ * HID;
    u16* Qt   = ws;
    u16* Kc   = Qt + QT_E;
    u16* Vc   = Kc + QT_E;
    u16* Wbf  = Vc + QT_E;
    u16* weff = Wbf + (size_t)2 * O3 * C_;
    u16* Xt   = (u16*)d_out;                  // scratch phase

    k_prep     <<<dim3(448),       dim3(256), 0, stream>>>(ew0, ew1, ow0, ow1, Wbf, weff);
    k_transpose<<<dim3(36, 4, 16), dim3(256), 0, stream>>>(x0, x1, Xt);
    k_embed    <<<dim3(36, 6, 16), dim3(256), 0, stream>>>(Xt, Wbf, eb0, eb1, Qt, Kc, Vc);
    k_attn_out <<<dim3(576),       dim3(256), 0, stream>>>(Qt, Kc, Vc, weff, ob0, ob1,
                                                           x0, x1, (float*)d_out);
}

// Round 6
// 211.461 us; speedup vs baseline: 1.5131x; 1.2864x over previous
//
#include <hip/hip_runtime.h>
#include <stdint.h>

// Problem constants
#define B_   8
#define C_   256
#define N_   2304          // 48*48 spatial
#define HID  128
#define O3   384           // 3*HID
#define NH   4
#define SCALE 0.0625f      // 256^-0.5
#define QPRE 0.09016844f   // SCALE * log2(e): q pre-scale so p = exp2(q.k)

typedef unsigned short u16;
typedef short  bf8  __attribute__((ext_vector_type(8)));   // 8 bf16 (4 VGPRs) MFMA A/B frag
typedef float  f4   __attribute__((ext_vector_type(4)));   // MFMA C/D frag
typedef u16    u16x8 __attribute__((ext_vector_type(8)));

#define MFMA(a,b,c) __builtin_amdgcn_mfma_f32_16x16x32_bf16((a),(b),(c),0,0,0)

static __device__ __forceinline__ u16 f2bf(float f){
    union { float f; unsigned int i; } v; v.f = f;
    unsigned int r = v.i + 0x7FFFu + ((v.i >> 16) & 1u);   // round-to-nearest-even
    return (u16)(r >> 16);
}
static __device__ __forceinline__ float fexp2(float x){
#if __has_builtin(__builtin_amdgcn_exp2f)
    return __builtin_amdgcn_exp2f(x);
#else
    return __expf(x * 0.69314718f);
#endif
}
static __device__ __forceinline__ u16 hi16(float f){       // truncating f32->bf16
    union { float f; unsigned int i; } v; v.f = f;
    return (u16)(v.i >> 16);
}
// async global->LDS DMA, 16B per lane; LDS dest is wave-uniform base + lane*16.
static __device__ __forceinline__ void dma16(const void* g, void* l){
    __builtin_amdgcn_global_load_lds(
        (const __attribute__((address_space(1))) void*)g,
        (__attribute__((address_space(3))) void*)l, 16, 0, 0);
}

// ---------------------------------------------------------------------------
// K0: merged weight prep (one launch).
//   blocks [0,192)  : embed weights fp32 -> bf16
//   blocks [192,448): w_eff^T[s][oc][hc] = sum_head out_w_s[head*HID+hc][oc]
__global__ __launch_bounds__(256) void k_prep(const float* __restrict__ ew0,
                                              const float* __restrict__ ew1,
                                              const float* __restrict__ ow0,
                                              const float* __restrict__ ow1,
                                              u16* __restrict__ Wbf,
                                              u16* __restrict__ weff){
    int bid = blockIdx.x;
    if (bid < 192){
        int s = bid >= 96 ? 1 : 0;
        int xb = bid - s*96;
        const float* w = s ? ew1 : ew0;
        u16* o = Wbf + (size_t)s * (O3 * C_);
        int idx = (xb * 256 + threadIdx.x) * 4;
        float4 v = *reinterpret_cast<const float4*>(&w[idx]);
        o[idx+0] = f2bf(v.x); o[idx+1] = f2bf(v.y);
        o[idx+2] = f2bf(v.z); o[idx+3] = f2bf(v.w);
    } else {
        int gid = (bid - 192) * 256 + threadIdx.x;   // 2*128*256 = 65536
        int oc = gid & 255, hc = (gid >> 8) & 127, s = gid >> 15;
        const float* w = s ? ow1 : ow0;
        float acc = 0.f;
        #pragma unroll
        for (int h = 0; h < NH; ++h) acc += w[(h*HID + hc)*C_ + oc];
        weff[(s*C_ + oc)*HID + hc] = f2bf(acc);
    }
}

// ---------------------------------------------------------------------------
// K1: FUSED transpose + embed GEMM (replaces k_transpose + k_embed; removes
// the Xt HBM round-trip entirely).
// Per block (n-tile n0 = bx*64, stream-batch z = by): stage X[z][c][n0..n0+64)
// fp32 -> Xs[n][c] bf16 via in-LDS transpose (tmp tile stride 65: the old
// k_transpose stride-72 readout was a 16-way bank conflict -- 8-row step was
// bank-0 aligned; 65 gives 2-way), then 6 x (64o x 64n, K=256) MFMA GEMM with
// vectorized stores: GEMM output staged to an LDS tile and written out as
// 16B/lane u16x8 stores matching the chunk-interleaved consumer layouts (the
// old k_embed did 16 scattered scalar u16 stores per thread).
// Output layouts (consumed by k_attn_out):
//   Qc: elem (n,h)  at (n>>4)*2048 + (h>>3)*128 + (n&15)*8 + (h&7)   [q*QPRE]
//   Kc: elem (n,h)  at ((n>>6)*16 + (h>>3))*512 + (n&63)*8 + (h&7)
//   Vc: elem (hc,n) at ((n>>6)*8 + ((n>>3)&7))*1024 + hc*8 + (n&7)
// LDS: Xs 64x272 u16 (34816 B; stride 272 -> ~2-way on b128 frag reads)
//      tile 64x72 u16 (9216 B; stride 65 in phase A, 72 as Es in phase B)
//      total 44032 B -> 3 blocks/CU, 576 blocks all resident.
__global__ __launch_bounds__(256, 3) void k_embed_fused(
        const float* __restrict__ x0, const float* __restrict__ x1,
        const u16* __restrict__ Wbf,
        const float* __restrict__ b0, const float* __restrict__ b1,
        u16* __restrict__ Qc, u16* __restrict__ Kc, u16* __restrict__ Vc){
    __shared__ __align__(16) u16 Xs[64*272];
    __shared__ __align__(16) u16 tile[64*72];
    int z = blockIdx.y, bb = z >> 1, s = z & 1;
    const float* X = (s ? x1 : x0) + (size_t)bb * (C_ * N_);
    const u16* W = Wbf + (size_t)s * (O3 * C_);
    const float* bias = s ? b1 : b0;
    int n0 = blockIdx.x * 64;
    int t = threadIdx.x;
    int lane = t & 63, wave = t >> 6;
    int l16 = lane & 15, quad = lane >> 4;

    // ---- Phase A: X[c][n] fp32 -> Xs[n][c] bf16, 4 c-subtiles of 64 --------
    {
        int lr = t >> 4, lc = (t & 15) * 4;
        int row = t >> 3, col8 = (t & 7) * 8;
        for (int cb = 0; cb < 4; ++cb){
            int c0 = cb * 64;
            #pragma unroll
            for (int rep = 0; rep < 4; ++rep){
                int c = lr + rep * 16;
                float4 v = *reinterpret_cast<const float4*>(
                    &X[(size_t)(c0 + c) * N_ + n0 + lc]);
                tile[c*65 + lc+0] = f2bf(v.x); tile[c*65 + lc+1] = f2bf(v.y);
                tile[c*65 + lc+2] = f2bf(v.z); tile[c*65 + lc+3] = f2bf(v.w);
            }
            __syncthreads();
            #pragma unroll
            for (int rep = 0; rep < 2; ++rep){
                int n = row + rep * 32;
                u16x8 v;
                #pragma unroll
                for (int j = 0; j < 8; ++j) v[j] = tile[(col8 + j)*65 + n];
                *reinterpret_cast<u16x8*>(&Xs[n*272 + c0 + col8]) = v;
            }
            __syncthreads();
        }
    }

    // ---- Phase B: 6 o-groups of 64; GEMM K=256 then staged vector store ----
    size_t zq = (size_t)z * (N_ * HID);
    int ncw = n0 >> 6;
    for (int og = 0; og < 6; ++og){
        int o0 = og*64 + wave*16;
        f4 acc[4] = {f4{0,0,0,0}, f4{0,0,0,0}, f4{0,0,0,0}, f4{0,0,0,0}};
        #pragma unroll
        for (int kk = 0; kk < 8; ++kk){
            bf8 a = *reinterpret_cast<const bf8*>(&W[(o0 + l16)*C_ + kk*32 + quad*8]);
            #pragma unroll
            for (int nt = 0; nt < 4; ++nt){
                bf8 bv = *reinterpret_cast<const bf8*>(
                    &Xs[(nt*16 + l16)*272 + kk*32 + quad*8]);
                acc[nt] = MFMA(a, bv, acc[nt]);
            }
        }
        // bias (+ QPRE for Q), stage to Es = tile (stride 72)
        float4 bv4 = *reinterpret_cast<const float4*>(&bias[o0 + quad*4]);
        float bb4[4] = {bv4.x, bv4.y, bv4.z, bv4.w};
        #pragma unroll
        for (int nt = 0; nt < 4; ++nt)
            #pragma unroll
            for (int r = 0; r < 4; ++r){
                float e = acc[nt][r] + bb4[r];
                if (og < 2) e *= QPRE;
                tile[(wave*16 + quad*4 + r)*72 + nt*16 + l16] = f2bf(e);
            }
        __syncthreads();
        // vectorized store: 512 u16x8 vecs = 2 per thread
        #pragma unroll
        for (int rep = 0; rep < 2; ++rep){
            int idx = t + rep*256;
            if (og < 2){                       // Q: h = og*64 + g8*8 + j
                int n = idx & 63, g8 = idx >> 6;
                u16x8 v;
                #pragma unroll
                for (int j = 0; j < 8; ++j) v[j] = tile[(g8*8 + j)*72 + n];
                int ng = n0 + n;
                *reinterpret_cast<u16x8*>(&Qc[zq + (size_t)(ng>>4)*2048
                        + (og*8 + g8)*128 + (ng & 15)*8]) = v;
            } else if (og < 4){                // K: h-128 = (og-2)*64 + cc*8 + j
                int n = idx & 63, cc = idx >> 6;
                u16x8 v;
                #pragma unroll
                for (int j = 0; j < 8; ++j) v[j] = tile[(cc*8 + j)*72 + n];
                *reinterpret_cast<u16x8*>(&Kc[zq
                        + (size_t)(ncw*16 + (og-2)*8 + cc)*512 + n*8]) = v;
            } else {                           // V: hc = (og-4)*64 + hl; vec over n&7
                int hl = idx & 63, p = idx >> 6;
                u16x8 v = *reinterpret_cast<const u16x8*>(&tile[hl*72 + p*8]);
                *reinterpret_cast<u16x8*>(&Vc[zq + (size_t)(ncw*8 + p)*1024
                        + ((og-4)*64 + hl)*8]) = v;
            }
        }
        __syncthreads();
    }
}

// ---------------------------------------------------------------------------
// K2 (fused): max-free flash attention + output projection + residual.
//   EXACT v1 structure (96.6 us: K/V staged per 64-key chunk via coalesced
//   global_load_lds, 2 barriers/chunk, per-wave P dbuf pad 72, 3 blocks/CU).
//   Only change: Q fragment loads use the tiled Qc layout.
__global__ __launch_bounds__(256, 3) void k_attn_out(const u16* __restrict__ Qt,
        const u16* __restrict__ Kc, const u16* __restrict__ Vc,
        const u16* __restrict__ weff,
        const float* __restrict__ ob0, const float* __restrict__ ob1,
        const float* __restrict__ x0, const float* __restrict__ x1,
        float* __restrict__ out){
    __shared__ __align__(16) u16 kbuf[64*128];      // 16 KB: (cc,n) at (cc*64+n)*8
    __shared__ __align__(16) u16 vbuf[64*128];      // 16 KB: (pc,hc) at (pc*128+hc)*8
    __shared__ __align__(16) u16 smem[8*16*72];     // P tiles (dbuf/wave); H tile in epilogue
    int bx = blockIdx.x;                      // 576 = 8 XCD * 72
    int xcd = bx & 7, t = bx >> 3;
    int z  = xcd*2 + (t >= 36 ? 1 : 0);       // XCD x serves z in {2x,2x+1}
    int mt = (t >= 36) ? (t - 36) : t;
    int b = z >> 1, s = z & 1;
    const u16* Q = Qt + (size_t)(b*2 + (1 - s)) * (N_ * HID);
    const u16* K = Kc + (size_t)(b*2 + s)       * (N_ * HID);
    const u16* V = Vc + (size_t)(b*2 + s)       * (N_ * HID);
    const u16* Wf   = weff + (size_t)s * (C_ * HID);
    const float* bias = s ? ob1 : ob0;
    const float* X = (s ? x1 : x0) + (size_t)b * (C_ * N_);
    float* O = out + (size_t)s * ((size_t)B_ * C_ * N_) + (size_t)b * (C_ * N_);
    int lane = threadIdx.x & 63, wave = threadIdx.x >> 6;
    int l16 = lane & 15, quad = lane >> 4;
    int m0 = mt * 64 + wave * 16;

    // Q frags from tiled Qc layout: frag(kk) at (m0>>4)*2048 + (kk*4+quad)*128 + l16*8
    bf8 aq[4];
    {
        const u16* Qb = Q + (size_t)(m0 >> 4)*2048 + l16*8;
        #pragma unroll
        for (int kk = 0; kk < 4; ++kk)
            aq[kk] = *reinterpret_cast<const bf8*>(&Qb[(kk*4 + quad)*128]);
    }

    bf8 ones;
    #pragma unroll
    for (int j = 0; j < 8; ++j) ones[j] = (short)0x3F80;   // bf16 1.0

    f4 oacc[8];
    #pragma unroll
    for (int ct = 0; ct < 8; ++ct) oacc[ct] = f4{0,0,0,0};
    f4 sumacc = f4{0,0,0,0};

    const char* Kb = (const char*)K;
    const char* Vb = (const char*)V;

    for (int nc = 0; nc < N_/64; ++nc){
        __syncthreads();                      // previous chunk's LDS reads done
        // stage K tile: issue ik -> 1 KB contiguous burst
        #pragma unroll
        for (int j = 0; j < 4; ++j){
            int ik = wave*4 + j;
            dma16(Kb + ((size_t)(nc*16 + ik)*512 + lane*8)*2, &kbuf[ik*512]);
        }
        // stage V tile: issue iv -> 1 KB contiguous burst
        #pragma unroll
        for (int j = 0; j < 4; ++j){
            int iv = wave*4 + j;
            dma16(Vb + ((size_t)(nc*8 + (iv>>1))*1024 + (iv&1)*512 + lane*8)*2,
                  &vbuf[iv*512]);
        }
        __syncthreads();                      // drains vmcnt(0): tiles visible
        // QK
        f4 sacc[4] = {f4{0,0,0,0}, f4{0,0,0,0}, f4{0,0,0,0}, f4{0,0,0,0}};
        #pragma unroll
        for (int kk = 0; kk < 4; ++kk)
            #pragma unroll
            for (int nt = 0; nt < 4; ++nt){
                bf8 bk = *reinterpret_cast<const bf8*>(&kbuf[((kk*4+quad)*64 + nt*16 + l16)*8]);
                sacc[nt] = MFMA(aq[kk], bk, sacc[nt]);
            }
        // p = exp2(s), truncating bf16 store to per-wave LDS (double-buffered)
        u16* pw = smem + (wave*2 + (nc & 1)) * (16*72);
        #pragma unroll
        for (int nt = 0; nt < 4; ++nt)
            #pragma unroll
            for (int r = 0; r < 4; ++r)
                pw[(quad*4 + r)*72 + nt*16 + l16] = hi16(fexp2(sacc[nt][r]));
        // PV + rowsum
        #pragma unroll
        for (int kk2 = 0; kk2 < 2; ++kk2){
            bf8 ap = *reinterpret_cast<const bf8*>(&pw[l16*72 + kk2*32 + quad*8]);
            sumacc = MFMA(ap, ones, sumacc);
            #pragma unroll
            for (int ct = 0; ct < 8; ++ct){
                bf8 bv = *reinterpret_cast<const bf8*>(&vbuf[((kk2*4+quad)*128 + ct*16 + l16)*8]);
                oacc[ct] = MFMA(ap, bv, oacc[ct]);
            }
        }
    }

    // normalize (lane-local: sumacc has same C-layout as oacc) and stash H
    __syncthreads();                           // P region dead in all waves
    float inv[4];
    #pragma unroll
    for (int r = 0; r < 4; ++r) inv[r] = 1.0f / sumacc[r];
    #pragma unroll
    for (int ct = 0; ct < 8; ++ct)
        #pragma unroll
        for (int r = 0; r < 4; ++r)
            smem[(wave*16 + quad*4 + r)*136 + ct*16 + l16] = f2bf(oacc[ct][r] * inv[r]);
    __syncthreads();

    // out GEMM: wave w -> oc [w*64, w*64+64); K = HID = 128
    int mb = mt * 64;
    int oc0 = wave * 64;
    f4 acc2[4][4];
    #pragma unroll
    for (int ot = 0; ot < 4; ++ot)
        #pragma unroll
        for (int nt = 0; nt < 4; ++nt) acc2[ot][nt] = f4{0,0,0,0};
    #pragma unroll
    for (int kk = 0; kk < 4; ++kk){
        bf8 bh[4];
        #pragma unroll
        for (int nt = 0; nt < 4; ++nt)
            bh[nt] = *reinterpret_cast<const bf8*>(&smem[(nt*16 + l16)*136 + kk*32 + quad*8]);
        #pragma unroll
        for (int ot = 0; ot < 4; ++ot){
            bf8 a = *reinterpret_cast<const bf8*>(&Wf[(oc0 + ot*16 + l16)*HID + kk*32 + quad*8]);
            #pragma unroll
            for (int nt = 0; nt < 4; ++nt)
                acc2[ot][nt] = MFMA(a, bh[nt], acc2[ot][nt]);
        }
    }
    #pragma unroll
    for (int ot = 0; ot < 4; ++ot)
        #pragma unroll
        for (int nt = 0; nt < 4; ++nt){
            int m = mb + nt*16 + l16;
            #pragma unroll
            for (int r = 0; r < 4; ++r){
                int oc = oc0 + ot*16 + quad*4 + r;
                O[(size_t)oc*N_ + m] = acc2[ot][nt][r] + bias[oc] + X[(size_t)oc*N_ + m];
            }
        }
}

// ---------------------------------------------------------------------------
extern "C" void kernel_launch(void* const* d_in, const int* in_sizes, int n_in,
                              void* d_out, int out_size, void* d_ws, size_t ws_size,
                              hipStream_t stream){
    const float* x0  = (const float*)d_in[0];
    const float* x1  = (const float*)d_in[1];
    const float* ew0 = (const float*)d_in[2];
    const float* eb0 = (const float*)d_in[3];
    const float* ew1 = (const float*)d_in[4];
    const float* eb1 = (const float*)d_in[5];
    const float* ow0 = (const float*)d_in[6];
    const float* ob0 = (const float*)d_in[7];
    const float* ow1 = (const float*)d_in[8];
    const float* ob1 = (const float*)d_in[9];

    u16* ws = (u16*)d_ws;
    const size_t QT_E = (size_t)16 * N_ * HID;
    u16* Qc   = ws;
    u16* Kc   = Qc + QT_E;
    u16* Vc   = Kc + QT_E;
    u16* Wbf  = Vc + QT_E;
    u16* weff = Wbf + (size_t)2 * O3 * C_;

    k_prep       <<<dim3(448),    dim3(256), 0, stream>>>(ew0, ew1, ow0, ow1, Wbf, weff);
    k_embed_fused<<<dim3(36, 16), dim3(256), 0, stream>>>(x0, x1, Wbf, eb0, eb1, Qc, Kc, Vc);
    k_attn_out   <<<dim3(576),    dim3(256), 0, stream>>>(Qc, Kc, Vc, weff, ob0, ob1,
                                                          x0, x1, (float*)d_out);
}